// Round 3
// baseline (458.939 us; speedup 1.0000x reference)
//
#include <hip/hip_runtime.h>

// Problem: B=2, L=2048, D=1024, H=16, Dh=64.  fp32 in/out (ref=np fp32!), int32 mask.
// Threshold = 8 bf16-ulps at max|out| (0.078) vs FULL-fp32 reference, so the QKV
// projection must be ~fp32-accurate: single-bf16-cast inputs give score errors
// ~30*sech2*sqrt(64)*2^-9 ~ 0.16 (observed R2). Fix: split-bf16 GEMM emulation
// (X=Xh+Xl, W=Wh+Wl, acc += XhWh+XhWl+XlWh) for Q,K; single-term for V.
// Kernel 2: flash attention, split-bf16 QK^T (Qh,Ql,Kh,Kl from kernel 1),
// single-bf16 P and V (error ~0.006 << 0.078).
//   MFMA C-layout: row = quad*4+reg, col = lane&15  [m89/m91]
//   MFMA A-layout: A[m=lane&15][k=quad*8+j]          [m120]

typedef unsigned short u16;
typedef __bf16 bf16x8 __attribute__((ext_vector_type(8)));
typedef float f32x4 __attribute__((ext_vector_type(4)));

#define MFMA(a, b, c) __builtin_amdgcn_mfma_f32_16x16x32_bf16(a, b, c, 0, 0, 0)

__device__ __forceinline__ u16 bf16rne(float f) {
    unsigned int u = __float_as_uint(f);
    u += 0x7fffu + ((u >> 16) & 1u);
    return (u16)(u >> 16);
}
__device__ __forceinline__ float bf16f(u16 h) {
    return __uint_as_float(((unsigned int)h) << 16);
}
__device__ __forceinline__ void split1(float f, u16& hi, u16& lo) {
    hi = bf16rne(f);
    lo = bf16rne(f - bf16f(hi));
}
__device__ __forceinline__ void split4(float4 v, ushort4& hi, ushort4& lo) {
    split1(v.x, hi.x, lo.x); split1(v.y, hi.y, lo.y);
    split1(v.z, hi.z, lo.z); split1(v.w, hi.w, lo.w);
}

// ---------------- Kernel 1: QKV projection GEMM (split-bf16 emulation) ----------------
// grid (48 n-blocks of 64 over 3072, 32 m-blocks of 128), 256 threads.
// LDS stride 40 bf16 (80B rows): 16B-aligned b128 frag reads, 2-way-max banks (free).
__global__ __launch_bounds__(256) void qkv_gemm(
    const float* __restrict__ X, const float* __restrict__ Wq,
    const float* __restrict__ Wk, const float* __restrict__ Wv,
    u16* __restrict__ Qh, u16* __restrict__ Ql,
    u16* __restrict__ Kh, u16* __restrict__ Kl,
    u16* __restrict__ VT)
{
    __shared__ __align__(16) u16 Ash[128 * 40];
    __shared__ __align__(16) u16 Asl[128 * 40];
    __shared__ __align__(16) u16 Bsh[64 * 40];
    __shared__ __align__(16) u16 Bsl[64 * 40];
    const int tid = threadIdx.x;
    const int wave = tid >> 6, lane = tid & 63, quad = lane >> 4, c16 = lane & 15;
    const int m0 = blockIdx.y * 128;
    const int n0 = blockIdx.x * 64;
    const int mat = n0 >> 10;                 // 0=Q, 1=K, 2=V
    const float* W = (mat == 0) ? Wq : ((mat == 1) ? Wk : Wv);
    const int nw = n0 & 1023;                 // col offset within this W
    const bool precise = (mat != 2);          // Q,K need split GEMM; V does not

    f32x4 acc[2][4];
#pragma unroll
    for (int i = 0; i < 2; i++)
#pragma unroll
        for (int j = 0; j < 4; j++) acc[i][j] = (f32x4){0.f, 0.f, 0.f, 0.f};

    for (int k0 = 0; k0 < 1024; k0 += 32) {
        // stage A (128x32) + B (64x32): fp32 global -> split bf16 hi/lo in LDS
#pragma unroll
        for (int i = 0; i < 4; i++) {   // A: 1024 float4 chunks / 256 threads
            int c = tid + i * 256;
            int row = c >> 3, kc = (c & 7) << 2;
            float4 v = *(const float4*)&X[(size_t)(m0 + row) * 1024 + k0 + kc];
            ushort4 h, l; split4(v, h, l);
            *(ushort4*)&Ash[row * 40 + kc] = h;
            *(ushort4*)&Asl[row * 40 + kc] = l;
        }
#pragma unroll
        for (int i = 0; i < 2; i++) {   // B: 512 float4 chunks / 256 threads
            int c = tid + i * 256;
            int row = c >> 3, kc = (c & 7) << 2;
            float4 v = *(const float4*)&W[(size_t)(nw + row) * 1024 + k0 + kc];
            ushort4 h, l; split4(v, h, l);
            *(ushort4*)&Bsh[row * 40 + kc] = h;
            *(ushort4*)&Bsl[row * 40 + kc] = l;
        }
        __syncthreads();
        bf16x8 ah[2], al[2], bh[4], bl[4];
#pragma unroll
        for (int mt = 0; mt < 2; mt++) {
            ah[mt] = *(const bf16x8*)&Ash[(wave * 32 + mt * 16 + c16) * 40 + quad * 8];
            al[mt] = *(const bf16x8*)&Asl[(wave * 32 + mt * 16 + c16) * 40 + quad * 8];
        }
#pragma unroll
        for (int nt = 0; nt < 4; nt++) {
            bh[nt] = *(const bf16x8*)&Bsh[(nt * 16 + c16) * 40 + quad * 8];
            bl[nt] = *(const bf16x8*)&Bsl[(nt * 16 + c16) * 40 + quad * 8];
        }
#pragma unroll
        for (int mt = 0; mt < 2; mt++)
#pragma unroll
            for (int nt = 0; nt < 4; nt++) {
                acc[mt][nt] = MFMA(ah[mt], bh[nt], acc[mt][nt]);
                if (precise) {
                    acc[mt][nt] = MFMA(ah[mt], bl[nt], acc[mt][nt]);
                    acc[mt][nt] = MFMA(al[mt], bh[nt], acc[mt][nt]);
                }
            }
        __syncthreads();
    }

    // epilogue: C[m][n] with m=token, n=feature; split hi/lo for Q,K; V transposed
#pragma unroll
    for (int mt = 0; mt < 2; mt++) {
#pragma unroll
        for (int nt = 0; nt < 4; nt++) {
#pragma unroll
            for (int reg = 0; reg < 4; reg++) {
                int m = m0 + wave * 32 + mt * 16 + quad * 4 + reg;
                int n = nw + nt * 16 + c16;
                int b_ = m >> 11, l = m & 2047;
                int h = n >> 6, dh = n & 63;
                float v = acc[mt][nt][reg];
                if (mat == 2) {
                    VT[((size_t)(b_ * 16 + h) * 64 + dh) * 2048 + l] = bf16rne(v);
                } else {
                    u16 hi, lo; split1(v, hi, lo);
                    size_t idx = ((size_t)(b_ * 16 + h) * 2048 + l) * 64 + dh;
                    if (mat == 0) { Qh[idx] = hi; Ql[idx] = lo; }
                    else          { Kh[idx] = hi; Kl[idx] = lo; }
                }
            }
        }
    }
}

// ---------------- Kernel 2: flash attention ----------------
// grid (32 q-tiles, 32 bh), 256 threads = 4 waves x 16 q-rows.
// LDS stride 72 bf16 (144B rows): 16B-aligned b128 frag reads.
__global__ __launch_bounds__(256) void attn(
    const u16* __restrict__ Qh, const u16* __restrict__ Ql,
    const u16* __restrict__ Kh, const u16* __restrict__ Kl,
    const u16* __restrict__ VT, const int* __restrict__ AM,
    float* __restrict__ Out)
{
    __shared__ __align__(16) u16 Khs[64 * 72];
    __shared__ __align__(16) u16 Kls[64 * 72];
    __shared__ __align__(16) u16 Vts[64 * 72];
    __shared__ __align__(16) u16 Qa[64 * 72];   // Qh tile, then reused as P staging
    __shared__ __align__(16) u16 Qb[64 * 72];   // Ql tile
    __shared__ int mk[64];

    const int tid = threadIdx.x, wave = tid >> 6, lane = tid & 63;
    const int quad = lane >> 4, c16 = lane & 15;
    const int qt = gridDim.x - 1 - blockIdx.x;      // heavy tiles dispatch first
    const int bh = blockIdx.y;
    const int b_ = bh >> 4, h = bh & 15;
    const int q0 = qt * 64;
    const size_t base = (size_t)bh * 2048 * 64;

    // stage Q tiles (64x64 hi + lo)
#pragma unroll
    for (int r = 0; r < 2; r++) {
        int c = tid + r * 256;
        int row = c >> 3, kc = (c & 7) << 3;
        *(uint4*)&Qa[row * 72 + kc] = *(const uint4*)&Qh[base + (size_t)(q0 + row) * 64 + kc];
        *(uint4*)&Qb[row * 72 + kc] = *(const uint4*)&Ql[base + (size_t)(q0 + row) * 64 + kc];
    }
    __syncthreads();
    bf16x8 qh0 = *(const bf16x8*)&Qa[(wave * 16 + c16) * 72 + quad * 8];
    bf16x8 qh1 = *(const bf16x8*)&Qa[(wave * 16 + c16) * 72 + 32 + quad * 8];
    bf16x8 ql0 = *(const bf16x8*)&Qb[(wave * 16 + c16) * 72 + quad * 8];
    bf16x8 ql1 = *(const bf16x8*)&Qb[(wave * 16 + c16) * 72 + 32 + quad * 8];

    float m_i[4], l_i[4];
    f32x4 o[4];
#pragma unroll
    for (int r = 0; r < 4; r++) { m_i[r] = -1e30f; l_i[r] = 0.f; o[r] = (f32x4){0.f, 0.f, 0.f, 0.f}; }

    for (int kb = 0; kb <= qt; ++kb) {
        const int k0 = kb * 64;
        // stage Kh/Kl/VT blocks + mask  (prev-iter reads protected by loop-end sync)
#pragma unroll
        for (int r = 0; r < 2; r++) {
            int c = tid + r * 256;
            int row = c >> 3, kc = (c & 7) << 3;
            *(uint4*)&Khs[row * 72 + kc] = *(const uint4*)&Kh[base + (size_t)(k0 + row) * 64 + kc];
            *(uint4*)&Kls[row * 72 + kc] = *(const uint4*)&Kl[base + (size_t)(k0 + row) * 64 + kc];
            *(uint4*)&Vts[row * 72 + kc] = *(const uint4*)&VT[(size_t)bh * 64 * 2048 + (size_t)row * 2048 + k0 + kc];
        }
        if (tid < 64) mk[tid] = AM[b_ * 2048 + k0 + tid];
        __syncthreads();

        // S = (Qh+Ql)(Kh+Kl)^T  ~= QhKh + QhKl + QlKh   (scaled, tanh, masked)
        float s[4][4];
        float bm[4] = {-3e38f, -3e38f, -3e38f, -3e38f};
#pragma unroll
        for (int nt = 0; nt < 4; nt++) {
            bf16x8 kh0 = *(const bf16x8*)&Khs[(nt * 16 + c16) * 72 + quad * 8];
            bf16x8 kh1 = *(const bf16x8*)&Khs[(nt * 16 + c16) * 72 + 32 + quad * 8];
            bf16x8 kl0 = *(const bf16x8*)&Kls[(nt * 16 + c16) * 72 + quad * 8];
            bf16x8 kl1 = *(const bf16x8*)&Kls[(nt * 16 + c16) * 72 + 32 + quad * 8];
            f32x4 sa = (f32x4){0.f, 0.f, 0.f, 0.f};
            sa = MFMA(qh0, kh0, sa);
            sa = MFMA(qh1, kh1, sa);
            sa = MFMA(ql0, kh0, sa);
            sa = MFMA(ql1, kh1, sa);
            sa = MFMA(qh0, kl0, sa);
            sa = MFMA(qh1, kl1, sa);
            const int key = k0 + nt * 16 + c16;
            const bool mok = (mk[nt * 16 + c16] != 0);
#pragma unroll
            for (int reg = 0; reg < 4; reg++) {
                int qg = q0 + wave * 16 + quad * 4 + reg;
                float x = sa[reg] * 0.125f;           // /sqrt(64)
                float e = __expf(2.f * x);
                float t = 30.f * (1.f - 2.f / (e + 1.f));   // 30*tanh(x)
                float val = ((key <= qg) && mok) ? t : -1e9f;
                s[nt][reg] = val;
                bm[reg] = fmaxf(bm[reg], val);
            }
        }
        // row max across the 16 lanes that own a row
#pragma unroll
        for (int reg = 0; reg < 4; reg++) {
#pragma unroll
            for (int off = 1; off < 16; off <<= 1)
                bm[reg] = fmaxf(bm[reg], __shfl_xor(bm[reg], off));
        }
        float alpha[4], rs[4];
#pragma unroll
        for (int reg = 0; reg < 4; reg++) {
            float mn = fmaxf(m_i[reg], bm[reg]);
            alpha[reg] = __expf(m_i[reg] - mn);
            m_i[reg] = mn;
            rs[reg] = 0.f;
        }
#pragma unroll
        for (int nt = 0; nt < 4; nt++)
#pragma unroll
            for (int reg = 0; reg < 4; reg++) {
                float p = __expf(s[nt][reg] - m_i[reg]);
                s[nt][reg] = p;
                rs[reg] += p;
            }
#pragma unroll
        for (int reg = 0; reg < 4; reg++) {
#pragma unroll
            for (int off = 1; off < 16; off <<= 1)
                rs[reg] += __shfl_xor(rs[reg], off);
            l_i[reg] = l_i[reg] * alpha[reg] + rs[reg];
        }
#pragma unroll
        for (int dt = 0; dt < 4; dt++)
#pragma unroll
            for (int reg = 0; reg < 4; reg++)
                o[dt][reg] *= alpha[reg];

        // P: C-layout -> LDS -> A-layout (wave-private rows of Qa)
#pragma unroll
        for (int nt = 0; nt < 4; nt++)
#pragma unroll
            for (int reg = 0; reg < 4; reg++)
                Qa[(wave * 16 + quad * 4 + reg) * 72 + nt * 16 + c16] = bf16rne(s[nt][reg]);
        __syncthreads();

        bf16x8 p0 = *(const bf16x8*)&Qa[(wave * 16 + c16) * 72 + quad * 8];
        bf16x8 p1 = *(const bf16x8*)&Qa[(wave * 16 + c16) * 72 + 32 + quad * 8];
#pragma unroll
        for (int dt = 0; dt < 4; dt++) {
            bf16x8 v0 = *(const bf16x8*)&Vts[(dt * 16 + c16) * 72 + quad * 8];
            bf16x8 v1 = *(const bf16x8*)&Vts[(dt * 16 + c16) * 72 + 32 + quad * 8];
            o[dt] = MFMA(p0, v0, o[dt]);
            o[dt] = MFMA(p1, v1, o[dt]);
        }
        __syncthreads();   // all reads of Khs/Kls/Vts done before next staging
    }

    // epilogue: out[b][q][h*64+d] = o/l   (fp32 output)
#pragma unroll
    for (int reg = 0; reg < 4; reg++) l_i[reg] = 1.f / l_i[reg];
#pragma unroll
    for (int dt = 0; dt < 4; dt++)
#pragma unroll
        for (int reg = 0; reg < 4; reg++) {
            int qg = q0 + wave * 16 + quad * 4 + reg;
            int d = dt * 16 + c16;
            Out[((size_t)b_ * 2048 + qg) * 1024 + h * 64 + d] = o[dt][reg] * l_i[reg];
        }
}

extern "C" void kernel_launch(void* const* d_in, const int* in_sizes, int n_in,
                              void* d_out, int out_size, void* d_ws, size_t ws_size,
                              hipStream_t stream) {
    const float* X  = (const float*)d_in[0];
    const int*   AM = (const int*)d_in[1];
    const float* Wq = (const float*)d_in[2];
    const float* Wk = (const float*)d_in[3];
    const float* Wv = (const float*)d_in[4];
    float* out = (float*)d_out;

    const size_t NE = (size_t)2 * 16 * 2048 * 64;   // 4.19M elems per tensor
    u16* Qh = (u16*)d_ws;
    u16* Ql = Qh + NE;
    u16* Kh = Ql + NE;
    u16* Kl = Kh + NE;
    u16* VT = Kl + NE;                               // total 41.9 MB of ws

    qkv_gemm<<<dim3(48, 32), 256, 0, stream>>>(X, Wq, Wk, Wv, Qh, Ql, Kh, Kl, VT);
    attn<<<dim3(32, 32), 256, 0, stream>>>(Qh, Ql, Kh, Kl, VT, AM, out);
}

// Round 4
// 305.316 us; speedup vs baseline: 1.5032x; 1.5032x over previous
//
#include <hip/hip_runtime.h>

// B=2, L=2048, D=1024, H=16, Dh=64. fp32 in/out, int32 mask. ref = full-fp32 np.
// Pipeline:
//  K0 presplit: X,Wq,Wk -> (hi,lo) bf16 pairs; Wv -> bf16. (one-time VALU cost)
//  K1 qkv_gemm: m97-style 128x128 tile, BK=32, global_load_lds(16B), bf16 MFMA.
//     Q/K use 3-term split GEMM as a K=3072 loop: segs [Xh*Wh | Xh*Wl | Xl*Wh].
//     Epilogue: Q scaled by 1/8 (exact), Q/K split to hi/lo (B,H,L,Dh); V -> (B,H,Dh,L).
//  K2 attn: flash tile 64 q-rows x 64 keys. tanh-bounded softmax: S<=30 always, so
//     fixed max: p = e^{S-30} = e^{-60/(e^{2x}+1)} -- no running max/alpha/rescale;
//     l summed per-lane, reduced once after the k-loop.
//  MFMA C-layout: row=quad*4+reg, col=lane&15 [m89/m91]; A-layout: A[lane&15][quad*8+j] [m120].

typedef unsigned short u16;
typedef __bf16 bf16x8 __attribute__((ext_vector_type(8)));
typedef float f32x4 __attribute__((ext_vector_type(4)));

#define MFMA(a, b, c) __builtin_amdgcn_mfma_f32_16x16x32_bf16(a, b, c, 0, 0, 0)

__device__ __forceinline__ u16 bf16rne(float f) {
    unsigned int u = __float_as_uint(f);
    u += 0x7fffu + ((u >> 16) & 1u);
    return (u16)(u >> 16);
}
__device__ __forceinline__ float bf16f(u16 h) {
    return __uint_as_float(((unsigned int)h) << 16);
}
__device__ __forceinline__ void split1(float f, u16& hi, u16& lo) {
    hi = bf16rne(f);
    lo = bf16rne(f - bf16f(hi));
}

// async global->LDS, 16B per lane. LDS side must be uniform_base + lane*16.
__device__ __forceinline__ void gl16(const u16* g, u16* l) {
    __builtin_amdgcn_global_load_lds(
        (const __attribute__((address_space(1))) unsigned int*)g,
        (__attribute__((address_space(3))) unsigned int*)l, 16, 0, 0);
}

// ---------------- Kernel 0: pre-split fp32 -> bf16 hi/lo ----------------
// f4-unit segments: X 1048576 | Wq 262144 | Wk 262144 | Wv 262144
__global__ __launch_bounds__(256) void presplit(
    const float* __restrict__ X, const float* __restrict__ Wq,
    const float* __restrict__ Wk, const float* __restrict__ Wv,
    u16* __restrict__ Xh, u16* __restrict__ Xl,
    u16* __restrict__ Wqh, u16* __restrict__ Wql,
    u16* __restrict__ Wkh, u16* __restrict__ Wkl,
    u16* __restrict__ Wvh)
{
    int i = blockIdx.x * 256 + threadIdx.x;
    const float* src; u16 *dh, *dl; int off;
    if (i < 1048576)      { src = X;  dh = Xh;  dl = Xl;      off = i; }
    else if (i < 1310720) { src = Wq; dh = Wqh; dl = Wql;     off = i - 1048576; }
    else if (i < 1572864) { src = Wk; dh = Wkh; dl = Wkl;     off = i - 1310720; }
    else                  { src = Wv; dh = Wvh; dl = nullptr; off = i - 1572864; }
    float4 v = ((const float4*)src)[off];
    ushort4 h, l;
    split1(v.x, h.x, l.x); split1(v.y, h.y, l.y);
    split1(v.z, h.z, l.z); split1(v.w, h.w, l.w);
    ((ushort4*)dh)[off] = h;
    if (dl) ((ushort4*)dl)[off] = l;
}

// ---------------- Kernel 1: QKV GEMM (m97 structure) ----------------
// grid (24 n-blocks, 32 m-blocks): nb/8 = mat (0=Q,1=K,2=V), 128x128 tile, 4 waves 2x2.
__global__ __launch_bounds__(256) void qkv_gemm(
    const u16* __restrict__ Xh, const u16* __restrict__ Xl,
    const u16* __restrict__ Wqh, const u16* __restrict__ Wql,
    const u16* __restrict__ Wkh, const u16* __restrict__ Wkl,
    const u16* __restrict__ Wvh,
    u16* __restrict__ Qh, u16* __restrict__ Ql,
    u16* __restrict__ Kh, u16* __restrict__ Kl,
    u16* __restrict__ VT)
{
    __shared__ __align__(16) u16 As[128 * 32];
    __shared__ __align__(16) u16 Bs[128 * 32];
    const int tid = threadIdx.x;
    const int wave = tid >> 6, lane = tid & 63, quad = lane >> 4, c16 = lane & 15;
    const int m0 = blockIdx.y * 128;
    const int nb = blockIdx.x;
    const int mat = nb >> 3;
    const int n0 = (nb & 7) * 128;
    const u16* Bh = (mat == 0) ? Wqh : ((mat == 1) ? Wkh : Wvh);
    const u16* Bl = (mat == 0) ? Wql : Wkl;
    const int nkt = (mat < 2) ? 96 : 32;
    const int wm = (wave >> 1) * 64, wn = (wave & 1) * 64;

    // staging geometry (per sweep s=0,1): row = wave*32+s*16+(lane>>2), col_u16 = (lane&3)*8
    const int srow0 = wave * 32 + (lane >> 2), scol = (lane & 3) * 8;

    f32x4 acc[4][4];
#pragma unroll
    for (int i = 0; i < 4; i++)
#pragma unroll
        for (int j = 0; j < 4; j++) acc[i][j] = (f32x4){0.f, 0.f, 0.f, 0.f};

    for (int kt = 0; kt < nkt; kt++) {
        const int seg = kt >> 5, kcol = (kt & 31) * 32;
        const u16* Ab = ((seg < 2) ? Xh : Xl) + (size_t)m0 * 1024 + kcol;
        const u16* Bb = ((seg == 1) ? Bl : Bh) + (size_t)n0 * 1024 + kcol;
#pragma unroll
        for (int s = 0; s < 2; s++) {
            int row = srow0 + s * 16;
            gl16(Ab + (size_t)row * 1024 + scol, &As[row * 32 + scol]);
            gl16(Bb + (size_t)row * 1024 + scol, &Bs[row * 32 + scol]);
        }
        __syncthreads();
        bf16x8 af[4], bfr[4];
#pragma unroll
        for (int mt = 0; mt < 4; mt++)
            af[mt] = *(const bf16x8*)&As[(wm + mt * 16 + c16) * 32 + quad * 8];
#pragma unroll
        for (int nt = 0; nt < 4; nt++)
            bfr[nt] = *(const bf16x8*)&Bs[(wn + nt * 16 + c16) * 32 + quad * 8];
#pragma unroll
        for (int mt = 0; mt < 4; mt++)
#pragma unroll
            for (int nt = 0; nt < 4; nt++)
                acc[mt][nt] = MFMA(af[mt], bfr[nt], acc[mt][nt]);
        __syncthreads();
    }

    const float scale = (mat == 0) ? 0.125f : 1.f;   // fold 1/sqrt(Dh) into Q (exact)
#pragma unroll
    for (int mt = 0; mt < 4; mt++) {
#pragma unroll
        for (int nt = 0; nt < 4; nt++) {
#pragma unroll
            for (int reg = 0; reg < 4; reg++) {
                int m = m0 + wm + mt * 16 + quad * 4 + reg;
                int n = n0 + wn + nt * 16 + c16;
                int b_ = m >> 11, l = m & 2047;
                int h = n >> 6, dh = n & 63;
                float v = acc[mt][nt][reg] * scale;
                if (mat == 2) {
                    VT[((b_ * 16 + h) * 64 + dh) * 2048 + l] = bf16rne(v);
                } else {
                    u16 hi, lo; split1(v, hi, lo);
                    int idx = ((b_ * 16 + h) * 2048 + l) * 64 + dh;
                    if (mat == 0) { Qh[idx] = hi; Ql[idx] = lo; }
                    else          { Kh[idx] = hi; Kl[idx] = lo; }
                }
            }
        }
    }
}

// ---------------- Kernel 2: flash attention, bounded softmax ----------------
// grid (32 q-tiles, 32 bh), 256 threads = 4 waves x 16 q-rows.
// LDS tiles: stacked pairs of 64x32-u16 subtiles (stride 32) for global_load_lds.
__global__ __launch_bounds__(256) void attn(
    const u16* __restrict__ Qh, const u16* __restrict__ Ql,
    const u16* __restrict__ Kh, const u16* __restrict__ Kl,
    const u16* __restrict__ VT, const int* __restrict__ AM,
    float* __restrict__ Out)
{
    __shared__ __align__(16) u16 Khs[4096];
    __shared__ __align__(16) u16 Kls[4096];
    __shared__ __align__(16) u16 Vs[4096];
    __shared__ __align__(16) u16 Qhs[4096];   // reused as P staging after frag load
    __shared__ __align__(16) u16 Qls[4096];

    const int tid = threadIdx.x, wave = tid >> 6, lane = tid & 63;
    const int quad = lane >> 4, c16 = lane & 15;
    const int qt = 31 - blockIdx.x;            // heavy tiles dispatch first
    const int bh = blockIdx.y;
    const int b_ = bh >> 4, h = bh & 15;
    const int q0 = qt * 64;
    const size_t base = (size_t)bh * 2048 * 64;
    u16* const Ps = Qhs;

    // staging geometry: sweep w = wave*2+s: sub = w>>2, row = (w&3)*16+(lane>>2), col=(lane&3)*8
    const int swsub[2] = { (wave * 2) >> 2, (wave * 2 + 1) >> 2 };
    const int swrow[2] = { ((wave * 2) & 3) * 16 + (lane >> 2), ((wave * 2 + 1) & 3) * 16 + (lane >> 2) };
    const int scol = (lane & 3) * 8;

    {   // stage Q hi/lo (each global tile: 64 rows x 128B, contiguous)
        const u16* Qht = Qh + base + (size_t)q0 * 64;
        const u16* Qlt = Ql + base + (size_t)q0 * 64;
#pragma unroll
        for (int s = 0; s < 2; s++) {
            int sub = swsub[s], row = swrow[s];
            int lo = sub * 2048 + row * 32 + scol;
            gl16(Qht + (size_t)row * 64 + sub * 32 + scol, &Qhs[lo]);
            gl16(Qlt + (size_t)row * 64 + sub * 32 + scol, &Qls[lo]);
        }
    }
    __syncthreads();
    bf16x8 qh0 = *(const bf16x8*)&Qhs[(wave * 16 + c16) * 32 + quad * 8];
    bf16x8 qh1 = *(const bf16x8*)&Qhs[2048 + (wave * 16 + c16) * 32 + quad * 8];
    bf16x8 ql0 = *(const bf16x8*)&Qls[(wave * 16 + c16) * 32 + quad * 8];
    bf16x8 ql1 = *(const bf16x8*)&Qls[2048 + (wave * 16 + c16) * 32 + quad * 8];

    float rsl[4] = {0.f, 0.f, 0.f, 0.f};
    f32x4 o[4];
#pragma unroll
    for (int r = 0; r < 4; r++) o[r] = (f32x4){0.f, 0.f, 0.f, 0.f};

    for (int kb = 0; kb <= qt; ++kb) {
        const int k0 = kb * 64;
        const u16* Kht = Kh + base + (size_t)k0 * 64;
        const u16* Klt = Kl + base + (size_t)k0 * 64;
        const u16* Vt  = VT + (size_t)bh * 64 * 2048 + k0;   // rows = d (stride 2048), cols = key
#pragma unroll
        for (int s = 0; s < 2; s++) {
            int sub = swsub[s], row = swrow[s];
            int lo = sub * 2048 + row * 32 + scol;
            gl16(Kht + (size_t)row * 64 + sub * 32 + scol, &Khs[lo]);
            gl16(Klt + (size_t)row * 64 + sub * 32 + scol, &Kls[lo]);
            gl16(Vt + (size_t)row * 2048 + sub * 32 + scol, &Vs[lo]);
        }
        __syncthreads();

        const bool interior = (kb < qt);
        float p[4][4];
#pragma unroll
        for (int nt = 0; nt < 4; nt++) {
            bf16x8 kh0 = *(const bf16x8*)&Khs[(nt * 16 + c16) * 32 + quad * 8];
            bf16x8 kh1 = *(const bf16x8*)&Khs[2048 + (nt * 16 + c16) * 32 + quad * 8];
            bf16x8 kl0 = *(const bf16x8*)&Kls[(nt * 16 + c16) * 32 + quad * 8];
            bf16x8 kl1 = *(const bf16x8*)&Kls[2048 + (nt * 16 + c16) * 32 + quad * 8];
            f32x4 sa = (f32x4){0.f, 0.f, 0.f, 0.f};
            sa = MFMA(qh0, kh0, sa);
            sa = MFMA(qh1, kh1, sa);
            sa = MFMA(ql0, kh0, sa);
            sa = MFMA(ql1, kh1, sa);
            sa = MFMA(qh0, kl0, sa);
            sa = MFMA(qh1, kl1, sa);
            const int key = k0 + nt * 16 + c16;
            const bool mok = (AM[b_ * 2048 + key] != 0);
#pragma unroll
            for (int reg = 0; reg < 4; reg++) {
                int qg = q0 + wave * 16 + quad * 4 + reg;
                float x = sa[reg];                       // already scaled by 1/8 via Q
                float e1 = __expf(2.f * x);              // e^{2x}; inf-safe (p->1)
                float r  = __builtin_amdgcn_rcpf(e1 + 1.f);
                float pv = __expf(-60.f * r);            // e^{30 tanh(x) - 30} in [e^-60, 1]
                bool keep = mok && (interior || key <= qg);
                pv = keep ? pv : 0.f;
                p[nt][reg] = pv;
                rsl[reg] += pv;
            }
        }

        // P: C-layout regs -> A-layout LDS (wave-private rows; barrier orders vs Khs/Kls reads)
#pragma unroll
        for (int nt = 0; nt < 4; nt++) {
            int kl_ = nt * 16 + c16, sub = kl_ >> 5, kc = kl_ & 31;
#pragma unroll
            for (int reg = 0; reg < 4; reg++)
                Ps[sub * 2048 + (wave * 16 + quad * 4 + reg) * 32 + kc] = bf16rne(p[nt][reg]);
        }
        __syncthreads();

        bf16x8 p0 = *(const bf16x8*)&Ps[(wave * 16 + c16) * 32 + quad * 8];
        bf16x8 p1 = *(const bf16x8*)&Ps[2048 + (wave * 16 + c16) * 32 + quad * 8];
#pragma unroll
        for (int dt = 0; dt < 4; dt++) {
            bf16x8 v0 = *(const bf16x8*)&Vs[(dt * 16 + c16) * 32 + quad * 8];
            bf16x8 v1 = *(const bf16x8*)&Vs[2048 + (dt * 16 + c16) * 32 + quad * 8];
            o[dt] = MFMA(p0, v0, o[dt]);
            o[dt] = MFMA(p1, v1, o[dt]);
        }
        __syncthreads();   // protect Vs/Khs/Kls before next staging
    }

    // l: reduce per-lane partials across the 16 lanes sharing each row (no rescale needed)
#pragma unroll
    for (int reg = 0; reg < 4; reg++) {
#pragma unroll
        for (int off = 1; off < 16; off <<= 1)
            rsl[reg] += __shfl_xor(rsl[reg], off);
        rsl[reg] = __builtin_amdgcn_rcpf(rsl[reg]);
    }
#pragma unroll
    for (int dt = 0; dt < 4; dt++)
#pragma unroll
        for (int reg = 0; reg < 4; reg++) {
            int qg = q0 + wave * 16 + quad * 4 + reg;
            int d = dt * 16 + c16;
            Out[(size_t)(b_ * 2048 + qg) * 1024 + h * 64 + d] = o[dt][reg] * rsl[reg];
        }
}

extern "C" void kernel_launch(void* const* d_in, const int* in_sizes, int n_in,
                              void* d_out, int out_size, void* d_ws, size_t ws_size,
                              hipStream_t stream) {
    const float* X  = (const float*)d_in[0];
    const int*   AM = (const int*)d_in[1];
    const float* Wq = (const float*)d_in[2];
    const float* Wk = (const float*)d_in[3];
    const float* Wv = (const float*)d_in[4];
    float* out = (float*)d_out;

    const size_t NE = (size_t)2 * 16 * 2048 * 64;   // 4.19M
    const size_t WN = (size_t)1024 * 1024;          // 1.05M
    u16* Qh  = (u16*)d_ws;
    u16* Ql  = Qh + NE;
    u16* Kh  = Ql + NE;
    u16* Kl  = Kh + NE;
    u16* VT  = Kl + NE;
    u16* Xh  = VT + NE;
    u16* Xl  = Xh + NE;      // X is 4096*1024 = NE elems
    u16* Wqh = Xl + NE;
    u16* Wql = Wqh + WN;
    u16* Wkh = Wql + WN;
    u16* Wkl = Wkh + WN;
    u16* Wvh = Wkl + WN;     // total ~69.2 MB

    presplit<<<7168, 256, 0, stream>>>(X, Wq, Wk, Wv, Xh, Xl, Wqh, Wql, Wkh, Wkl, Wvh);
    qkv_gemm<<<dim3(24, 32), 256, 0, stream>>>(Xh, Xl, Wqh, Wql, Wkh, Wkl, Wvh,
                                               Qh, Ql, Kh, Kl, VT);
    attn<<<dim3(32, 32), 256, 0, stream>>>(Qh, Ql, Kh, Kl, VT, AM, out);
}

// Round 5
// 257.905 us; speedup vs baseline: 1.7795x; 1.1838x over previous
//
#include <hip/hip_runtime.h>

// B=2, L=2048, D=1024, H=16, Dh=64. fp32 in/out, int32 mask. ref = full-fp32 np.
//  K0 presplit: X,Wq,Wk -> (hi,lo) bf16; Wv -> bf16.
//  K1 qkv_gemm: 128x128 tile, BK=32, global_load_lds(16B), DOUBLE-BUFFERED (1 barrier/iter),
//     Q/K as 3-term split GEMM (K=3072 segs XhWh|XhWl|XlWh). XCD swizzle: n-block pinned.
//  K2 attn: paired q-tiles (qt, 31-qt) -> 33 k-units/block, 512 blocks = 2/CU, bh-major
//     grid => all pairs of a bh on one XCD. Double-buffered K/V staging, 1 barrier/iter;
//     P C->A layout roundtrip is wave-private LDS (no barrier). Bounded softmax
//     p = e^{30 tanh(x) - 30} (no running max/rescale).
//  MFMA C-layout: row=quad*4+reg, col=lane&15 [m89/m91]; A-layout: A[lane&15][quad*8+j] [m120].

typedef unsigned short u16;
typedef __bf16 bf16x8 __attribute__((ext_vector_type(8)));
typedef float f32x4 __attribute__((ext_vector_type(4)));

#define MFMA(a, b, c) __builtin_amdgcn_mfma_f32_16x16x32_bf16(a, b, c, 0, 0, 0)

__device__ __forceinline__ u16 bf16rne(float f) {
    unsigned int u = __float_as_uint(f);
    u += 0x7fffu + ((u >> 16) & 1u);
    return (u16)(u >> 16);
}
__device__ __forceinline__ float bf16f(u16 h) {
    return __uint_as_float(((unsigned int)h) << 16);
}
__device__ __forceinline__ void split1(float f, u16& hi, u16& lo) {
    hi = bf16rne(f);
    lo = bf16rne(f - bf16f(hi));
}

// async global->LDS, 16B per lane. LDS side must be uniform_base + lane*16.
__device__ __forceinline__ void gl16(const u16* g, u16* l) {
    __builtin_amdgcn_global_load_lds(
        (const __attribute__((address_space(1))) unsigned int*)g,
        (__attribute__((address_space(3))) unsigned int*)l, 16, 0, 0);
}

// ---------------- Kernel 0: pre-split fp32 -> bf16 hi/lo ----------------
__global__ __launch_bounds__(256) void presplit(
    const float* __restrict__ X, const float* __restrict__ Wq,
    const float* __restrict__ Wk, const float* __restrict__ Wv,
    u16* __restrict__ Xh, u16* __restrict__ Xl,
    u16* __restrict__ Wqh, u16* __restrict__ Wql,
    u16* __restrict__ Wkh, u16* __restrict__ Wkl,
    u16* __restrict__ Wvh)
{
    int i = blockIdx.x * 256 + threadIdx.x;
    const float* src; u16 *dh, *dl; int off;
    if (i < 1048576)      { src = X;  dh = Xh;  dl = Xl;      off = i; }
    else if (i < 1310720) { src = Wq; dh = Wqh; dl = Wql;     off = i - 1048576; }
    else if (i < 1572864) { src = Wk; dh = Wkh; dl = Wkl;     off = i - 1310720; }
    else                  { src = Wv; dh = Wvh; dl = nullptr; off = i - 1572864; }
    float4 v = ((const float4*)src)[off];
    ushort4 h, l;
    split1(v.x, h.x, l.x); split1(v.y, h.y, l.y);
    split1(v.z, h.z, l.z); split1(v.w, h.w, l.w);
    ((ushort4*)dh)[off] = h;
    if (dl) ((ushort4*)dl)[off] = l;
}

// ---------------- Kernel 1: QKV GEMM (double-buffered) ----------------
// 768 blocks; swizzle: id = (m*3 + nb_hi)*8 + nb_lo  => all m of one nb share an XCD.
__global__ __launch_bounds__(256) void qkv_gemm(
    const u16* __restrict__ Xh, const u16* __restrict__ Xl,
    const u16* __restrict__ Wqh, const u16* __restrict__ Wql,
    const u16* __restrict__ Wkh, const u16* __restrict__ Wkl,
    const u16* __restrict__ Wvh,
    u16* __restrict__ Qh, u16* __restrict__ Ql,
    u16* __restrict__ Kh, u16* __restrict__ Kl,
    u16* __restrict__ VT)
{
    __shared__ __align__(16) u16 As[2][4096];
    __shared__ __align__(16) u16 Bs[2][4096];
    const int tid = threadIdx.x;
    const int wave = tid >> 6, lane = tid & 63, quad = lane >> 4, c16 = lane & 15;
    const int id = blockIdx.x;
    const int nb = (((id >> 3) % 3) << 3) | (id & 7);   // 0..23
    const int m  = (id >> 3) / 3;                        // 0..31
    const int m0 = m * 128;
    const int mat = nb >> 3;
    const int n0 = (nb & 7) * 128;
    const u16* Bh = (mat == 0) ? Wqh : ((mat == 1) ? Wkh : Wvh);
    const u16* Bl = (mat == 0) ? Wql : Wkl;
    const int nkt = (mat < 2) ? 96 : 32;
    const int wm = (wave >> 1) * 64, wn = (wave & 1) * 64;

    const int srow0 = wave * 32 + (lane >> 2), scol = (lane & 3) * 8;

    f32x4 acc[4][4];
#pragma unroll
    for (int i = 0; i < 4; i++)
#pragma unroll
        for (int j = 0; j < 4; j++) acc[i][j] = (f32x4){0.f, 0.f, 0.f, 0.f};

    // stage(kt, buf)
    auto stage = [&](int kt, int buf) {
        const int seg = kt >> 5, kcol = (kt & 31) * 32;
        const u16* Ab = ((seg < 2) ? Xh : Xl) + (size_t)m0 * 1024 + kcol;
        const u16* Bb = ((seg == 1) ? Bl : Bh) + (size_t)n0 * 1024 + kcol;
#pragma unroll
        for (int s = 0; s < 2; s++) {
            int row = srow0 + s * 16;
            gl16(Ab + (size_t)row * 1024 + scol, &As[buf][row * 32 + scol]);
            gl16(Bb + (size_t)row * 1024 + scol, &Bs[buf][row * 32 + scol]);
        }
    };

    stage(0, 0);
    int cur = 0;
    for (int kt = 0; kt < nkt; kt++) {
        __syncthreads();                       // buf[cur] staged; prev reads of buf[cur^1] done
        if (kt + 1 < nkt) stage(kt + 1, cur ^ 1);
        bf16x8 af[4], bfr[4];
#pragma unroll
        for (int mt = 0; mt < 4; mt++)
            af[mt] = *(const bf16x8*)&As[cur][(wm + mt * 16 + c16) * 32 + quad * 8];
#pragma unroll
        for (int nt = 0; nt < 4; nt++)
            bfr[nt] = *(const bf16x8*)&Bs[cur][(wn + nt * 16 + c16) * 32 + quad * 8];
#pragma unroll
        for (int mt = 0; mt < 4; mt++)
#pragma unroll
            for (int nt = 0; nt < 4; nt++)
                acc[mt][nt] = MFMA(af[mt], bfr[nt], acc[mt][nt]);
        cur ^= 1;
    }

    const float scale = (mat == 0) ? 0.125f : 1.f;   // fold 1/sqrt(Dh) into Q (exact)
#pragma unroll
    for (int mt = 0; mt < 4; mt++) {
#pragma unroll
        for (int nt = 0; nt < 4; nt++) {
#pragma unroll
            for (int reg = 0; reg < 4; reg++) {
                int mm = m0 + wm + mt * 16 + quad * 4 + reg;
                int n = n0 + wn + nt * 16 + c16;
                int b_ = mm >> 11, l = mm & 2047;
                int h = n >> 6, dh = n & 63;
                float v = acc[mt][nt][reg] * scale;
                if (mat == 2) {
                    VT[((b_ * 16 + h) * 64 + dh) * 2048 + l] = bf16rne(v);
                } else {
                    u16 hi, lo; split1(v, hi, lo);
                    int idx = ((b_ * 16 + h) * 2048 + l) * 64 + dh;
                    if (mat == 0) { Qh[idx] = hi; Ql[idx] = lo; }
                    else          { Kh[idx] = hi; Kl[idx] = lo; }
                }
            }
        }
    }
}

// ---------------- Kernel 2: flash attention, paired tiles + dbuf ----------------
// grid (32 bh, 16 pair): block does q-tiles {31-p, p} -> 33 k-units each. 2 blocks/CU.
__global__ __launch_bounds__(256) void attn(
    const u16* __restrict__ Qh, const u16* __restrict__ Ql,
    const u16* __restrict__ Kh, const u16* __restrict__ Kl,
    const u16* __restrict__ VT, const int* __restrict__ AM,
    float* __restrict__ Out)
{
    __shared__ __align__(16) u16 Khs[2][4096];
    __shared__ __align__(16) u16 Kls[2][4096];
    __shared__ __align__(16) u16 Vs[2][4096];
    __shared__ __align__(16) u16 Qhs[4096];   // aliased as P staging (Q frags live in regs)
    __shared__ __align__(16) u16 Qls[4096];

    const int tid = threadIdx.x, wave = tid >> 6, lane = tid & 63;
    const int quad = lane >> 4, c16 = lane & 15;
    const int bh = blockIdx.x;                 // fast dim => all pairs of a bh on one XCD
    const int pr = blockIdx.y;                 // 0..15
    const int b_ = bh >> 4, h = bh & 15;
    const size_t base = (size_t)bh * 2048 * 64;
    u16* const Ps = Qhs;

    const int swsub[2] = { (wave * 2) >> 2, (wave * 2 + 1) >> 2 };
    const int swrow[2] = { ((wave * 2) & 3) * 16 + (lane >> 2), ((wave * 2 + 1) & 3) * 16 + (lane >> 2) };
    const int scol = (lane & 3) * 8;

    auto stageKV = [&](int k0, int buf) {
        const u16* Kht = Kh + base + (size_t)k0 * 64;
        const u16* Klt = Kl + base + (size_t)k0 * 64;
        const u16* Vt  = VT + (size_t)bh * 64 * 2048 + k0;
#pragma unroll
        for (int s = 0; s < 2; s++) {
            int sub = swsub[s], row = swrow[s];
            int lo = sub * 2048 + row * 32 + scol;
            gl16(Kht + (size_t)row * 64 + sub * 32 + scol, &Khs[buf][lo]);
            gl16(Klt + (size_t)row * 64 + sub * 32 + scol, &Kls[buf][lo]);
            gl16(Vt + (size_t)row * 2048 + sub * 32 + scol, &Vs[buf][lo]);
        }
    };

    for (int tix = 0; tix < 2; ++tix) {
        const int qt = tix ? pr : 31 - pr;     // heavy tile first
        const int q0 = qt * 64;
        {   // stage Q hi/lo + kb=0 K/V
            const u16* Qht = Qh + base + (size_t)q0 * 64;
            const u16* Qlt = Ql + base + (size_t)q0 * 64;
#pragma unroll
            for (int s = 0; s < 2; s++) {
                int sub = swsub[s], row = swrow[s];
                int lo = sub * 2048 + row * 32 + scol;
                gl16(Qht + (size_t)row * 64 + sub * 32 + scol, &Qhs[lo]);
                gl16(Qlt + (size_t)row * 64 + sub * 32 + scol, &Qls[lo]);
            }
            stageKV(0, 0);
        }
        __syncthreads();
        bf16x8 qh0 = *(const bf16x8*)&Qhs[(wave * 16 + c16) * 32 + quad * 8];
        bf16x8 qh1 = *(const bf16x8*)&Qhs[2048 + (wave * 16 + c16) * 32 + quad * 8];
        bf16x8 ql0 = *(const bf16x8*)&Qls[(wave * 16 + c16) * 32 + quad * 8];
        bf16x8 ql1 = *(const bf16x8*)&Qls[2048 + (wave * 16 + c16) * 32 + quad * 8];

        float rsl[4] = {0.f, 0.f, 0.f, 0.f};
        f32x4 o[4];
#pragma unroll
        for (int r = 0; r < 4; r++) o[r] = (f32x4){0.f, 0.f, 0.f, 0.f};

        int cur = 0;
        for (int kb = 0; kb <= qt; ++kb) {
            const int k0 = kb * 64;
            if (kb < qt) stageKV(k0 + 64, cur ^ 1);
            const int mkv = AM[b_ * 2048 + k0 + lane];   // mask for this key block
            const bool interior = (kb < qt);

            float p[4][4];
#pragma unroll
            for (int nt = 0; nt < 4; nt++) {
                bf16x8 kh0 = *(const bf16x8*)&Khs[cur][(nt * 16 + c16) * 32 + quad * 8];
                bf16x8 kh1 = *(const bf16x8*)&Khs[cur][2048 + (nt * 16 + c16) * 32 + quad * 8];
                bf16x8 kl0 = *(const bf16x8*)&Kls[cur][(nt * 16 + c16) * 32 + quad * 8];
                bf16x8 kl1 = *(const bf16x8*)&Kls[cur][2048 + (nt * 16 + c16) * 32 + quad * 8];
                f32x4 sa = (f32x4){0.f, 0.f, 0.f, 0.f};
                sa = MFMA(qh0, kh0, sa);
                sa = MFMA(qh1, kh1, sa);
                sa = MFMA(ql0, kh0, sa);
                sa = MFMA(ql1, kh1, sa);
                sa = MFMA(qh0, kl0, sa);
                sa = MFMA(qh1, kl1, sa);
                const int key = k0 + nt * 16 + c16;
                const bool mok = (__shfl(mkv, nt * 16 + c16) != 0);
#pragma unroll
                for (int reg = 0; reg < 4; reg++) {
                    int qg = q0 + wave * 16 + quad * 4 + reg;
                    float x = sa[reg];                       // pre-scaled by 1/8 via Q
                    float e1 = __expf(2.f * x);              // inf-safe (p->1)
                    float r  = __builtin_amdgcn_rcpf(e1 + 1.f);
                    float pv = __expf(-60.f * r);            // e^{30 tanh(x)-30} in [e^-60,1]
                    bool keep = mok && (interior || key <= qg);
                    pv = keep ? pv : 0.f;
                    p[nt][reg] = pv;
                    rsl[reg] += pv;
                }
            }

            // P: C-layout -> A-layout via wave-private LDS rows (in-order DS pipe: no barrier)
#pragma unroll
            for (int nt = 0; nt < 4; nt++) {
                int kl_ = nt * 16 + c16, sub = kl_ >> 5, kc = kl_ & 31;
#pragma unroll
                for (int reg = 0; reg < 4; reg++)
                    Ps[sub * 2048 + (wave * 16 + quad * 4 + reg) * 32 + kc] = bf16rne(p[nt][reg]);
            }
            bf16x8 p0 = *(const bf16x8*)&Ps[(wave * 16 + c16) * 32 + quad * 8];
            bf16x8 p1 = *(const bf16x8*)&Ps[2048 + (wave * 16 + c16) * 32 + quad * 8];
#pragma unroll
            for (int dt = 0; dt < 4; dt++) {
                bf16x8 v0 = *(const bf16x8*)&Vs[cur][(dt * 16 + c16) * 32 + quad * 8];
                bf16x8 v1 = *(const bf16x8*)&Vs[cur][2048 + (dt * 16 + c16) * 32 + quad * 8];
                o[dt] = MFMA(p0, v0, o[dt]);
                o[dt] = MFMA(p1, v1, o[dt]);
            }
            __syncthreads();   // next buf staged (prefetch had full compute to land); reads done
            cur ^= 1;
        }

        // l: reduce across the 16 lanes sharing each row (no rescale with bounded softmax)
        float inv[4];
#pragma unroll
        for (int reg = 0; reg < 4; reg++) {
            float v = rsl[reg];
#pragma unroll
            for (int off = 1; off < 16; off <<= 1)
                v += __shfl_xor(v, off);
            inv[reg] = __builtin_amdgcn_rcpf(v);
        }
#pragma unroll
        for (int dt = 0; dt < 4; dt++)
#pragma unroll
            for (int reg = 0; reg < 4; reg++) {
                int qg = q0 + wave * 16 + quad * 4 + reg;
                int d = dt * 16 + c16;
                Out[(size_t)(b_ * 2048 + qg) * 1024 + h * 64 + d] = o[dt][reg] * inv[reg];
            }
    }
}

extern "C" void kernel_launch(void* const* d_in, const int* in_sizes, int n_in,
                              void* d_out, int out_size, void* d_ws, size_t ws_size,
                              hipStream_t stream) {
    const float* X  = (const float*)d_in[0];
    const int*   AM = (const int*)d_in[1];
    const float* Wq = (const float*)d_in[2];
    const float* Wk = (const float*)d_in[3];
    const float* Wv = (const float*)d_in[4];
    float* out = (float*)d_out;

    const size_t NE = (size_t)2 * 16 * 2048 * 64;   // 4.19M
    const size_t WN = (size_t)1024 * 1024;          // 1.05M
    u16* Qh  = (u16*)d_ws;
    u16* Ql  = Qh + NE;
    u16* Kh  = Ql + NE;
    u16* Kl  = Kh + NE;
    u16* VT  = Kl + NE;
    u16* Xh  = VT + NE;
    u16* Xl  = Xh + NE;
    u16* Wqh = Xl + NE;
    u16* Wql = Wqh + WN;
    u16* Wkh = Wql + WN;
    u16* Wkl = Wkh + WN;
    u16* Wvh = Wkl + WN;     // ~69.2 MB total

    presplit<<<7168, 256, 0, stream>>>(X, Wq, Wk, Wv, Xh, Xl, Wqh, Wql, Wkh, Wkl, Wvh);
    qkv_gemm<<<768, 256, 0, stream>>>(Xh, Xl, Wqh, Wql, Wkh, Wkl, Wvh,
                                      Qh, Ql, Kh, Kl, VT);
    attn<<<dim3(32, 16), 256, 0, stream>>>(Qh, Ql, Kh, Kl, VT, AM, out);
}

// Round 6
// 249.318 us; speedup vs baseline: 1.8408x; 1.0344x over previous
//
#include <hip/hip_runtime.h>

// B=2, L=2048, D=1024, H=16, Dh=64. fp32 in/out, int32 mask. ref = full-fp32 np.
//  K0 presplit: X,Wq,Wk -> (hi,lo) bf16; Wv -> bf16.
//  K1 qkv_gemm: 128x128 tile, 32 k-iters, 4-tensor staging (Xh,Xl,Wh,Wl) in 32KB LDS,
//     48 MFMA/barrier-pair for Q/K (3-term split GEMM), 16 for V. m97-style 2 barriers.
//  K2 attn: only K in LDS (hi/lo dbuf, 1 barrier/iter). Q and V fragments loaded
//     DIRECTLY from global (contiguous 16B/lane in stored layouts). Bounded softmax
//     p = e^{30 tanh(x)-30} (fixed max) => ksplit partials combine by plain addition.
//     ksplit=2 + pair-balance: 1024 blocks = 4/CU co-resident, 16-17 k-units each.
//  K3 combine: out = (oA+oB)/(lA+lB).
//  MFMA C-layout: row=quad*4+reg, col=lane&15 [m89/m91]; A/B-layout: [lane&15][quad*8+j] [m120].

typedef unsigned short u16;
typedef __bf16 bf16x8 __attribute__((ext_vector_type(8)));
typedef float f32x4 __attribute__((ext_vector_type(4)));

#define MFMA(a, b, c) __builtin_amdgcn_mfma_f32_16x16x32_bf16(a, b, c, 0, 0, 0)

__device__ __forceinline__ u16 bf16rne(float f) {
    unsigned int u = __float_as_uint(f);
    u += 0x7fffu + ((u >> 16) & 1u);
    return (u16)(u >> 16);
}
__device__ __forceinline__ float bf16f(u16 h) {
    return __uint_as_float(((unsigned int)h) << 16);
}
__device__ __forceinline__ void split1(float f, u16& hi, u16& lo) {
    hi = bf16rne(f);
    lo = bf16rne(f - bf16f(hi));
}

// async global->LDS, 16B per lane. LDS dest must be uniform_base + lane*16.
__device__ __forceinline__ void gl16(const u16* g, u16* l) {
    __builtin_amdgcn_global_load_lds(
        (const __attribute__((address_space(1))) unsigned int*)g,
        (__attribute__((address_space(3))) unsigned int*)l, 16, 0, 0);
}

// ---------------- Kernel 0: pre-split fp32 -> bf16 hi/lo ----------------
__global__ __launch_bounds__(256) void presplit(
    const float* __restrict__ X, const float* __restrict__ Wq,
    const float* __restrict__ Wk, const float* __restrict__ Wv,
    u16* __restrict__ Xh, u16* __restrict__ Xl,
    u16* __restrict__ Wqh, u16* __restrict__ Wql,
    u16* __restrict__ Wkh, u16* __restrict__ Wkl,
    u16* __restrict__ Wvh)
{
    int i = blockIdx.x * 256 + threadIdx.x;
    const float* src; u16 *dh, *dl; int off;
    if (i < 1048576)      { src = X;  dh = Xh;  dl = Xl;      off = i; }
    else if (i < 1310720) { src = Wq; dh = Wqh; dl = Wql;     off = i - 1048576; }
    else if (i < 1572864) { src = Wk; dh = Wkh; dl = Wkl;     off = i - 1310720; }
    else                  { src = Wv; dh = Wvh; dl = nullptr; off = i - 1572864; }
    float4 v = ((const float4*)src)[off];
    ushort4 h, l;
    split1(v.x, h.x, l.x); split1(v.y, h.y, l.y);
    split1(v.z, h.z, l.z); split1(v.w, h.w, l.w);
    ((ushort4*)dh)[off] = h;
    if (dl) ((ushort4*)dl)[off] = l;
}

// ---------------- Kernel 1: QKV GEMM (4-tensor staging) ----------------
// 768 blocks; swizzle keeps all m-blocks of one n-block on one XCD.
__global__ __launch_bounds__(256, 4) void qkv_gemm(
    const u16* __restrict__ Xh, const u16* __restrict__ Xl,
    const u16* __restrict__ Wqh, const u16* __restrict__ Wql,
    const u16* __restrict__ Wkh, const u16* __restrict__ Wkl,
    const u16* __restrict__ Wvh,
    u16* __restrict__ Qh, u16* __restrict__ Ql,
    u16* __restrict__ Kh, u16* __restrict__ Kl,
    u16* __restrict__ VT)
{
    __shared__ __align__(16) u16 Xhs[4096];
    __shared__ __align__(16) u16 Xls[4096];
    __shared__ __align__(16) u16 Whs[4096];
    __shared__ __align__(16) u16 Wls[4096];
    const int tid = threadIdx.x;
    const int wave = tid >> 6, lane = tid & 63, quad = lane >> 4, c16 = lane & 15;
    const int id = blockIdx.x;
    const int nb = (((id >> 3) % 3) << 3) | (id & 7);   // 0..23
    const int m0 = ((id >> 3) / 3) * 128;
    const int mat = nb >> 3;
    const int n0 = (nb & 7) * 128;
    const u16* Bh = (mat == 0) ? Wqh : ((mat == 1) ? Wkh : Wvh);
    const u16* Bl = (mat == 0) ? Wql : Wkl;
    const int nseg = (mat < 2) ? 3 : 1;
    const int wm = (wave >> 1) * 64, wn = (wave & 1) * 64;

    const int srow0 = wave * 32 + (lane >> 2), scol = (lane & 3) * 8;

    f32x4 acc[4][4];
#pragma unroll
    for (int i = 0; i < 4; i++)
#pragma unroll
        for (int j = 0; j < 4; j++) acc[i][j] = (f32x4){0.f, 0.f, 0.f, 0.f};

    for (int kt = 0; kt < 32; kt++) {
        const int kcol = kt * 32;
#pragma unroll
        for (int s = 0; s < 2; s++) {
            int row = srow0 + s * 16;
            size_t go = (size_t)row * 1024 + kcol + scol;
            int lo = row * 32 + scol;
            gl16(Xh + (size_t)m0 * 1024 + go, &Xhs[lo]);
            gl16(Bh + (size_t)n0 * 1024 + go, &Whs[lo]);
            if (nseg == 3) {
                gl16(Xl + (size_t)m0 * 1024 + go, &Xls[lo]);
                gl16(Bl + (size_t)n0 * 1024 + go, &Wls[lo]);
            }
        }
        __syncthreads();
        for (int seg = 0; seg < nseg; seg++) {
            const u16* ap = (seg < 2) ? Xhs : Xls;
            const u16* bp = (seg == 1) ? Wls : Whs;
            bf16x8 af[4], bfr[4];
#pragma unroll
            for (int mt = 0; mt < 4; mt++)
                af[mt] = *(const bf16x8*)&ap[(wm + mt * 16 + c16) * 32 + quad * 8];
#pragma unroll
            for (int nt = 0; nt < 4; nt++)
                bfr[nt] = *(const bf16x8*)&bp[(wn + nt * 16 + c16) * 32 + quad * 8];
#pragma unroll
            for (int mt = 0; mt < 4; mt++)
#pragma unroll
                for (int nt = 0; nt < 4; nt++)
                    acc[mt][nt] = MFMA(af[mt], bfr[nt], acc[mt][nt]);
        }
        __syncthreads();
    }

    const float scale = (mat == 0) ? 0.125f : 1.f;   // fold 1/sqrt(Dh) into Q (exact)
#pragma unroll
    for (int mt = 0; mt < 4; mt++) {
#pragma unroll
        for (int nt = 0; nt < 4; nt++) {
#pragma unroll
            for (int reg = 0; reg < 4; reg++) {
                int mm = m0 + wm + mt * 16 + quad * 4 + reg;
                int n = n0 + wn + nt * 16 + c16;
                int b_ = mm >> 11, l = mm & 2047;
                int h = n >> 6, dh = n & 63;
                float v = acc[mt][nt][reg] * scale;
                if (mat == 2) {
                    VT[((b_ * 16 + h) * 64 + dh) * 2048 + l] = bf16rne(v);
                } else {
                    u16 hi, lo; split1(v, hi, lo);
                    int idx = ((b_ * 16 + h) * 2048 + l) * 64 + dh;
                    if (mat == 0) { Qh[idx] = hi; Ql[idx] = lo; }
                    else          { Kh[idx] = hi; Kl[idx] = lo; }
                }
            }
        }
    }
}

// ---------------- Kernel 2: flash attention, ksplit partials ----------------
// grid (32 bh, 16 pair, 2 split). Block: q-tiles {31-p, p}, k-blocks kb≡s (mod 2).
// K hi/lo in LDS dbuf (1 barrier/iter); Q,V frags direct from global; Ps wave-private.
__global__ __launch_bounds__(256, 4) void attn(
    const u16* __restrict__ Qh, const u16* __restrict__ Ql,
    const u16* __restrict__ Kh, const u16* __restrict__ Kl,
    const u16* __restrict__ VT, const int* __restrict__ AM,
    u16* __restrict__ Op, float* __restrict__ Lp)
{
    __shared__ __align__(16) u16 Khs[2][4096];
    __shared__ __align__(16) u16 Kls[2][4096];
    __shared__ __align__(16) u16 Ps[4096];

    const int tid = threadIdx.x, wave = tid >> 6, lane = tid & 63;
    const int quad = lane >> 4, c16 = lane & 15;
    const int bh = blockIdx.x;                 // fast dim => bh pinned to an XCD
    const int pr = blockIdx.y;                 // 0..15
    const int sp = blockIdx.z;                 // ksplit part 0/1
    const int b_ = bh >> 4;
    const size_t base = (size_t)bh * 2048 * 64;

    const int swsub[2] = { (wave * 2) >> 2, (wave * 2 + 1) >> 2 };
    const int swrow[2] = { ((wave * 2) & 3) * 16 + (lane >> 2), ((wave * 2 + 1) & 3) * 16 + (lane >> 2) };
    const int scol = (lane & 3) * 8;

    auto stageK = [&](int k0, int buf) {
        const u16* Kht = Kh + base + (size_t)k0 * 64;
        const u16* Klt = Kl + base + (size_t)k0 * 64;
#pragma unroll
        for (int s = 0; s < 2; s++) {
            int sub = swsub[s], row = swrow[s];
            int lo = sub * 2048 + row * 32 + scol;
            gl16(Kht + (size_t)row * 64 + sub * 32 + scol, &Khs[buf][lo]);
            gl16(Klt + (size_t)row * 64 + sub * 32 + scol, &Kls[buf][lo]);
        }
    };

    for (int tix = 0; tix < 2; ++tix) {
        const int qt = tix ? pr : 31 - pr;     // heavy tile first
        const int q0 = qt * 64;

        // Q fragments direct from global (A-layout rows contiguous: 16B/lane)
        const size_t qrow = base + (size_t)(q0 + wave * 16 + c16) * 64 + quad * 8;
        bf16x8 qh0 = *(const bf16x8*)&Qh[qrow];
        bf16x8 qh1 = *(const bf16x8*)&Qh[qrow + 32];
        bf16x8 ql0 = *(const bf16x8*)&Ql[qrow];
        bf16x8 ql1 = *(const bf16x8*)&Ql[qrow + 32];

        float rsl[4] = {0.f, 0.f, 0.f, 0.f};
        f32x4 o[4];
#pragma unroll
        for (int r = 0; r < 4; r++) o[r] = (f32x4){0.f, 0.f, 0.f, 0.f};

        if (sp <= qt) {
            stageK(sp * 64, 0);
            int cur = 0;
            for (int kb = sp; kb <= qt; kb += 2) {
                const int k0 = kb * 64;
                __syncthreads();                         // Khs[cur] landed; old reads done
                if (kb + 2 <= qt) stageK(k0 + 128, cur ^ 1);
                const int mkv = AM[b_ * 2048 + k0 + lane];
                const bool interior = (kb < qt);

                float p[4][4];
#pragma unroll
                for (int nt = 0; nt < 4; nt++) {
                    bf16x8 kh0 = *(const bf16x8*)&Khs[cur][(nt * 16 + c16) * 32 + quad * 8];
                    bf16x8 kh1 = *(const bf16x8*)&Khs[cur][2048 + (nt * 16 + c16) * 32 + quad * 8];
                    bf16x8 kl0 = *(const bf16x8*)&Kls[cur][(nt * 16 + c16) * 32 + quad * 8];
                    bf16x8 kl1 = *(const bf16x8*)&Kls[cur][2048 + (nt * 16 + c16) * 32 + quad * 8];
                    f32x4 sa = (f32x4){0.f, 0.f, 0.f, 0.f};
                    sa = MFMA(qh0, kh0, sa);
                    sa = MFMA(qh1, kh1, sa);
                    sa = MFMA(ql0, kh0, sa);
                    sa = MFMA(ql1, kh1, sa);
                    sa = MFMA(qh0, kl0, sa);
                    sa = MFMA(qh1, kl1, sa);
                    const int key = k0 + nt * 16 + c16;
                    const bool mok = (__shfl(mkv, nt * 16 + c16) != 0);
#pragma unroll
                    for (int reg = 0; reg < 4; reg++) {
                        int qg = q0 + wave * 16 + quad * 4 + reg;
                        float x = sa[reg];                       // pre-scaled by 1/8 via Q
                        float e1 = __expf(2.f * x);              // inf-safe (p->1)
                        float r  = __builtin_amdgcn_rcpf(e1 + 1.f);
                        float pv = __expf(-60.f * r);            // e^{30 tanh(x)-30}
                        bool keep = mok && (interior || key <= qg);
                        pv = keep ? pv : 0.f;
                        p[nt][reg] = pv;
                        rsl[reg] += pv;
                    }
                }

                // P: C-layout -> A-layout via wave-private LDS rows (in-order DS pipe)
#pragma unroll
                for (int nt = 0; nt < 4; nt++) {
                    int kl_ = nt * 16 + c16, sub = kl_ >> 5, kc = kl_ & 31;
#pragma unroll
                    for (int reg = 0; reg < 4; reg++)
                        Ps[sub * 2048 + (wave * 16 + quad * 4 + reg) * 32 + kc] = bf16rne(p[nt][reg]);
                }
                bf16x8 p0 = *(const bf16x8*)&Ps[(wave * 16 + c16) * 32 + quad * 8];
                bf16x8 p1 = *(const bf16x8*)&Ps[2048 + (wave * 16 + c16) * 32 + quad * 8];

                // V fragments direct from VT (B-layout rows contiguous: 16B/lane)
#pragma unroll
                for (int dt = 0; dt < 4; dt++) {
                    const size_t vrow = (size_t)(bh * 64 + dt * 16 + c16) * 2048 + k0 + quad * 8;
                    bf16x8 v0 = *(const bf16x8*)&VT[vrow];
                    bf16x8 v1 = *(const bf16x8*)&VT[vrow + 32];
                    o[dt] = MFMA(p0, v0, o[dt]);
                    o[dt] = MFMA(p1, v1, o[dt]);
                }
                cur ^= 1;
            }
        }
        __syncthreads();   // all K reads done before next tile's staging reuses buf 0

        // partial epilogue: o (bf16) and l (f32) per (sp, bh, qt)
        const size_t ob = ((size_t)(sp * 512 + bh * 16) + 0) * 0 +   // (compute below)
                          ((size_t)((sp * 32 + 0) ) * 0);
        (void)ob;
        const size_t obase = (((size_t)sp * 1024 + (size_t)bh * 32 + qt) * 4096);
        const size_t lbase = (((size_t)sp * 1024 + (size_t)bh * 32 + qt) * 64);
        float lsum[4];
#pragma unroll
        for (int reg = 0; reg < 4; reg++) {
            float v = rsl[reg];
#pragma unroll
            for (int off = 1; off < 16; off <<= 1)
                v += __shfl_xor(v, off);
            lsum[reg] = v;
        }
        if (c16 == 0) {
#pragma unroll
            for (int reg = 0; reg < 4; reg++)
                Lp[lbase + wave * 16 + quad * 4 + reg] = lsum[reg];
        }
#pragma unroll
        for (int dt = 0; dt < 4; dt++)
#pragma unroll
            for (int reg = 0; reg < 4; reg++) {
                int row = wave * 16 + quad * 4 + reg;
                int d = dt * 16 + c16;
                Op[obase + row * 64 + d] = bf16rne(o[dt][reg]);
            }
    }
}

// ---------------- Kernel 3: combine ksplit partials ----------------
__global__ __launch_bounds__(256) void combine(
    const u16* __restrict__ Op, const float* __restrict__ Lp,
    float* __restrict__ Out)
{
    const int i = blockIdx.x * 256 + threadIdx.x;   // 1048576 threads, 4 floats each
    const size_t lin = (size_t)i * 4;
    const int d  = (int)(lin & 1023);
    const int h  = d >> 6, dd = d & 63;
    const int l  = (int)((lin >> 10) & 2047);
    const int b  = (int)(lin >> 21);
    const int qt = l >> 6, row = l & 63;
    const int bh = b * 16 + h;
    const size_t o0 = (((size_t)bh * 32 + qt) * 4096) + row * 64 + dd;
    const size_t o1 = o0 + (size_t)1024 * 4096;
    const size_t l0 = (((size_t)bh * 32 + qt) * 64) + row;
    ushort4 pa = *(const ushort4*)&Op[o0];
    ushort4 pb = *(const ushort4*)&Op[o1];
    float inv = __builtin_amdgcn_rcpf(Lp[l0] + Lp[l0 + 65536]);
    float4 r;
    r.x = (bf16f(pa.x) + bf16f(pb.x)) * inv;
    r.y = (bf16f(pa.y) + bf16f(pb.y)) * inv;
    r.z = (bf16f(pa.z) + bf16f(pb.z)) * inv;
    r.w = (bf16f(pa.w) + bf16f(pb.w)) * inv;
    *(float4*)&Out[lin] = r;
}

extern "C" void kernel_launch(void* const* d_in, const int* in_sizes, int n_in,
                              void* d_out, int out_size, void* d_ws, size_t ws_size,
                              hipStream_t stream) {
    const float* X  = (const float*)d_in[0];
    const int*   AM = (const int*)d_in[1];
    const float* Wq = (const float*)d_in[2];
    const float* Wk = (const float*)d_in[3];
    const float* Wv = (const float*)d_in[4];
    float* out = (float*)d_out;

    const size_t NE = (size_t)2 * 16 * 2048 * 64;   // 4.19M elems
    const size_t WN = (size_t)1024 * 1024;
    u16* Qh  = (u16*)d_ws;
    u16* Ql  = Qh + NE;
    u16* Kh  = Ql + NE;
    u16* Kl  = Kh + NE;
    u16* VT  = Kl + NE;
    u16* Xh  = VT + NE;      // dead after qkv_gemm -> reused as Op (2*NE u16)
    u16* Xl  = Xh + NE;
    u16* Wqh = Xl + NE;      // dead after qkv_gemm -> reused as Lp (131072 f32)
    u16* Wql = Wqh + WN;
    u16* Wkh = Wql + WN;
    u16* Wkl = Wkh + WN;
    u16* Wvh = Wkl + WN;     // ~69.2 MB total
    u16*   Op = Xh;
    float* Lp = (float*)Wqh;

    presplit<<<7168, 256, 0, stream>>>(X, Wq, Wk, Wv, Xh, Xl, Wqh, Wql, Wkh, Wkl, Wvh);
    qkv_gemm<<<768, 256, 0, stream>>>(Xh, Xl, Wqh, Wql, Wkh, Wkl, Wvh,
                                      Qh, Ql, Kh, Kl, VT);
    attn<<<dim3(32, 16, 2), 256, 0, stream>>>(Qh, Ql, Kh, Kl, VT, AM, Op, Lp);
    combine<<<4096, 256, 0, stream>>>(Op, Lp, out);
}

// Round 7
// 237.185 us; speedup vs baseline: 1.9349x; 1.0512x over previous
//
#include <hip/hip_runtime.h>
#include <hip/hip_bf16.h>

// B=2, L=2048, D=1024, H=16, Dh=64. fp32 in/out, int32 mask. ref = full-fp32 np.
//  K0 presplit: X,Wq,Wk -> (hi,lo) bf16; Wv -> bf16.
//  K1 qkv_gemm: 128x128 tile, 32 k-iters, 4-tensor staging (Xh,Xl,Wh,Wl) in 32KB LDS,
//     48 MFMA/barrier-pair for Q/K (3-term split GEMM), 16 for V. V epilogue via
//     wave-private LDS transpose + v_cvt_pk_bf16_f32 -> coalesced 16B stores.
//  K2 attn: K hi/lo in LDS dbuf (1 barrier/iter); Q,V fragments + mask hoisted to
//     iter top, direct from global (contiguous 16B/lane). Bounded softmax
//     p = e^{30 tanh(x)-30} (fixed max) => ksplit partials combine by addition.
//     Pair-balance + ksplit=2: 1024 blocks = 4/CU, ~16.5 k-units each.
//  K3 combine: out = (oA+oB)/(lA+lB).
//  MFMA C-layout: row=quad*4+reg, col=lane&15 [m89/m91]; A/B-layout: [lane&15][quad*8+j] [m120].

typedef unsigned short u16;
typedef __bf16 bf16x8 __attribute__((ext_vector_type(8)));
typedef float f32x4 __attribute__((ext_vector_type(4)));

#define MFMA(a, b, c) __builtin_amdgcn_mfma_f32_16x16x32_bf16(a, b, c, 0, 0, 0)

__device__ __forceinline__ u16 bf16rne(float f) {
    unsigned int u = __float_as_uint(f);
    u += 0x7fffu + ((u >> 16) & 1u);
    return (u16)(u >> 16);
}
__device__ __forceinline__ float bf16f(u16 h) {
    return __uint_as_float(((unsigned int)h) << 16);
}
__device__ __forceinline__ void split1(float f, u16& hi, u16& lo) {
    hi = bf16rne(f);
    lo = bf16rne(f - bf16f(hi));
}
__device__ __forceinline__ unsigned int pk2(float a, float b) {   // v_cvt_pk_bf16_f32 (RNE)
    __hip_bfloat162 t = __float22bfloat162_rn(float2{a, b});
    return *(unsigned int*)&t;
}

// async global->LDS, 16B per lane. LDS dest must be uniform_base + lane*16.
__device__ __forceinline__ void gl16(const u16* g, u16* l) {
    __builtin_amdgcn_global_load_lds(
        (const __attribute__((address_space(1))) unsigned int*)g,
        (__attribute__((address_space(3))) unsigned int*)l, 16, 0, 0);
}

// ---------------- Kernel 0: pre-split fp32 -> bf16 hi/lo ----------------
__global__ __launch_bounds__(256) void presplit(
    const float* __restrict__ X, const float* __restrict__ Wq,
    const float* __restrict__ Wk, const float* __restrict__ Wv,
    u16* __restrict__ Xh, u16* __restrict__ Xl,
    u16* __restrict__ Wqh, u16* __restrict__ Wql,
    u16* __restrict__ Wkh, u16* __restrict__ Wkl,
    u16* __restrict__ Wvh)
{
    int i = blockIdx.x * 256 + threadIdx.x;
    const float* src; u16 *dh, *dl; int off;
    if (i < 1048576)      { src = X;  dh = Xh;  dl = Xl;      off = i; }
    else if (i < 1310720) { src = Wq; dh = Wqh; dl = Wql;     off = i - 1048576; }
    else if (i < 1572864) { src = Wk; dh = Wkh; dl = Wkl;     off = i - 1310720; }
    else                  { src = Wv; dh = Wvh; dl = nullptr; off = i - 1572864; }
    float4 v = ((const float4*)src)[off];
    ushort4 h, l;
    split1(v.x, h.x, l.x); split1(v.y, h.y, l.y);
    split1(v.z, h.z, l.z); split1(v.w, h.w, l.w);
    ((ushort4*)dh)[off] = h;
    if (dl) ((ushort4*)dl)[off] = l;
}

// ---------------- Kernel 1: QKV GEMM (4-tensor staging) ----------------
// 768 blocks; swizzle keeps all m-blocks of one n-block on one XCD.
__global__ __launch_bounds__(256, 4) void qkv_gemm(
    const u16* __restrict__ Xh, const u16* __restrict__ Xl,
    const u16* __restrict__ Wqh, const u16* __restrict__ Wql,
    const u16* __restrict__ Wkh, const u16* __restrict__ Wkl,
    const u16* __restrict__ Wvh,
    u16* __restrict__ Qh, u16* __restrict__ Ql,
    u16* __restrict__ Kh, u16* __restrict__ Kl,
    u16* __restrict__ VT)
{
    __shared__ __align__(16) u16 S[16384];    // staging 4x4096; epilogue transpose scratch
    u16* const Xhs = &S[0];
    u16* const Xls = &S[4096];
    u16* const Whs = &S[8192];
    u16* const Wls = &S[12288];
    const int tid = threadIdx.x;
    const int wave = tid >> 6, lane = tid & 63, quad = lane >> 4, c16 = lane & 15;
    const int id = blockIdx.x;
    const int nb = (((id >> 3) % 3) << 3) | (id & 7);   // 0..23
    const int m0 = ((id >> 3) / 3) * 128;
    const int mat = nb >> 3;
    const int n0 = (nb & 7) * 128;
    const u16* Bh = (mat == 0) ? Wqh : ((mat == 1) ? Wkh : Wvh);
    const u16* Bl = (mat == 0) ? Wql : Wkl;
    const int nseg = (mat < 2) ? 3 : 1;
    const int wm = (wave >> 1) * 64, wn = (wave & 1) * 64;

    const int srow0 = wave * 32 + (lane >> 2), scol = (lane & 3) * 8;

    f32x4 acc[4][4];
#pragma unroll
    for (int i = 0; i < 4; i++)
#pragma unroll
        for (int j = 0; j < 4; j++) acc[i][j] = (f32x4){0.f, 0.f, 0.f, 0.f};

    for (int kt = 0; kt < 32; kt++) {
        const int kcol = kt * 32;
#pragma unroll
        for (int s = 0; s < 2; s++) {
            int row = srow0 + s * 16;
            size_t go = (size_t)row * 1024 + kcol + scol;
            int lo = row * 32 + scol;
            gl16(Xh + (size_t)m0 * 1024 + go, &Xhs[lo]);
            gl16(Bh + (size_t)n0 * 1024 + go, &Whs[lo]);
            if (nseg == 3) {
                gl16(Xl + (size_t)m0 * 1024 + go, &Xls[lo]);
                gl16(Bl + (size_t)n0 * 1024 + go, &Wls[lo]);
            }
        }
        __syncthreads();
        for (int seg = 0; seg < nseg; seg++) {
            const u16* ap = (seg < 2) ? Xhs : Xls;
            const u16* bp = (seg == 1) ? Wls : Whs;
            bf16x8 af[4], bfr[4];
#pragma unroll
            for (int mt = 0; mt < 4; mt++)
                af[mt] = *(const bf16x8*)&ap[(wm + mt * 16 + c16) * 32 + quad * 8];
#pragma unroll
            for (int nt = 0; nt < 4; nt++)
                bfr[nt] = *(const bf16x8*)&bp[(wn + nt * 16 + c16) * 32 + quad * 8];
#pragma unroll
            for (int mt = 0; mt < 4; mt++)
#pragma unroll
                for (int nt = 0; nt < 4; nt++)
                    acc[mt][nt] = MFMA(af[mt], bfr[nt], acc[mt][nt]);
        }
        __syncthreads();
    }

    if (mat == 2) {
        // V epilogue: wave-private LDS transpose -> coalesced VT stores.
        // T2[n 0..63][m-half 0..31] u16 at wavebase + n*40 + m  (40: 16B-aligned rows, 2-way banks)
        u16* const T2 = &S[wave * 4096];
        const int nglob = n0 + wn + lane;
        const int hh = nglob >> 6, dh = nglob & 63;
        const int bh64 = ((m0 >> 11) * 16 + hh) * 64 + dh;   // m0 is 128-aligned; b = m0>>11
        u16* const vrow = VT + (size_t)bh64 * 2048 + (m0 & 2047) + wm;
#pragma unroll
        for (int half = 0; half < 2; half++) {
#pragma unroll
            for (int mt2 = 0; mt2 < 2; mt2++) {
                int mt = half * 2 + mt2;
#pragma unroll
                for (int nt = 0; nt < 4; nt++) {
                    uint2 d;
                    d.x = pk2(acc[mt][nt][0], acc[mt][nt][1]);
                    d.y = pk2(acc[mt][nt][2], acc[mt][nt][3]);
                    *(uint2*)&T2[(nt * 16 + c16) * 40 + mt2 * 16 + quad * 4] = d;
                }
            }
            // read row n=lane (32 u16 = 64B) and store contiguous to VT
#pragma unroll
            for (int c = 0; c < 4; c++) {
                uint4 d = *(const uint4*)&T2[lane * 40 + c * 8];
                *(uint4*)&vrow[half * 32 + c * 8] = d;
            }
        }
    } else {
        const float scale = (mat == 0) ? 0.125f : 1.f;   // fold 1/sqrt(Dh) into Q (exact)
#pragma unroll
        for (int mt = 0; mt < 4; mt++) {
#pragma unroll
            for (int nt = 0; nt < 4; nt++) {
#pragma unroll
                for (int reg = 0; reg < 4; reg++) {
                    int mm = m0 + wm + mt * 16 + quad * 4 + reg;
                    int n = n0 + wn + nt * 16 + c16;
                    int b_ = mm >> 11, l = mm & 2047;
                    int h = n >> 6, dh = n & 63;
                    float v = acc[mt][nt][reg] * scale;
                    u16 hi, lo; split1(v, hi, lo);
                    int idx = ((b_ * 16 + h) * 2048 + l) * 64 + dh;
                    if (mat == 0) { Qh[idx] = hi; Ql[idx] = lo; }
                    else          { Kh[idx] = hi; Kl[idx] = lo; }
                }
            }
        }
    }
}

// ---------------- Kernel 2: flash attention, ksplit partials ----------------
// grid (32 bh, 16 pair, 2 split). Block: q-tiles {31-p, p}, k-blocks kb≡sp (mod 2).
__global__ __launch_bounds__(256, 4) void attn(
    const u16* __restrict__ Qh, const u16* __restrict__ Ql,
    const u16* __restrict__ Kh, const u16* __restrict__ Kl,
    const u16* __restrict__ VT, const int* __restrict__ AM,
    u16* __restrict__ Op, float* __restrict__ Lp)
{
    __shared__ __align__(16) u16 Khs[2][4096];
    __shared__ __align__(16) u16 Kls[2][4096];
    __shared__ __align__(16) u16 Ps[4096];

    const int tid = threadIdx.x, wave = tid >> 6, lane = tid & 63;
    const int quad = lane >> 4, c16 = lane & 15;
    const int bh = blockIdx.x;                 // fast dim => bh pinned to an XCD
    const int pr = blockIdx.y;                 // 0..15
    const int sp = blockIdx.z;                 // ksplit part 0/1
    const int b_ = bh >> 4;
    const size_t base = (size_t)bh * 2048 * 64;

    const int swsub[2] = { (wave * 2) >> 2, (wave * 2 + 1) >> 2 };
    const int swrow[2] = { ((wave * 2) & 3) * 16 + (lane >> 2), ((wave * 2 + 1) & 3) * 16 + (lane >> 2) };
    const int scol = (lane & 3) * 8;

    auto stageK = [&](int k0, int buf) {
        const u16* Kht = Kh + base + (size_t)k0 * 64;
        const u16* Klt = Kl + base + (size_t)k0 * 64;
#pragma unroll
        for (int s = 0; s < 2; s++) {
            int sub = swsub[s], row = swrow[s];
            int lo = sub * 2048 + row * 32 + scol;
            gl16(Kht + (size_t)row * 64 + sub * 32 + scol, &Khs[buf][lo]);
            gl16(Klt + (size_t)row * 64 + sub * 32 + scol, &Kls[buf][lo]);
        }
    };

    for (int tix = 0; tix < 2; ++tix) {
        const int qt = tix ? pr : 31 - pr;     // heavy tile first
        const int q0 = qt * 64;

        // Q fragments direct from global (A-layout rows contiguous: 16B/lane)
        const size_t qrow = base + (size_t)(q0 + wave * 16 + c16) * 64 + quad * 8;
        bf16x8 qh0 = *(const bf16x8*)&Qh[qrow];
        bf16x8 qh1 = *(const bf16x8*)&Qh[qrow + 32];
        bf16x8 ql0 = *(const bf16x8*)&Ql[qrow];
        bf16x8 ql1 = *(const bf16x8*)&Ql[qrow + 32];

        float rsl[4] = {0.f, 0.f, 0.f, 0.f};
        f32x4 o[4];
#pragma unroll
        for (int r = 0; r < 4; r++) o[r] = (f32x4){0.f, 0.f, 0.f, 0.f};

        if (sp <= qt) {
            stageK(sp * 64, 0);
            int cur = 0;
            for (int kb = sp; kb <= qt; kb += 2) {
                const int k0 = kb * 64;
                __syncthreads();                         // Khs[cur] landed; old reads done
                if (kb + 2 <= qt) stageK(k0 + 128, cur ^ 1);

                // HOISTED: mask + V fragments issued before QK so latency is covered
                int mk[4];
#pragma unroll
                for (int nt = 0; nt < 4; nt++)
                    mk[nt] = AM[b_ * 2048 + k0 + nt * 16 + c16];
                bf16x8 vf[4][2];
#pragma unroll
                for (int dt = 0; dt < 4; dt++) {
                    const size_t vrow = (size_t)(bh * 64 + dt * 16 + c16) * 2048 + k0 + quad * 8;
                    vf[dt][0] = *(const bf16x8*)&VT[vrow];
                    vf[dt][1] = *(const bf16x8*)&VT[vrow + 32];
                }
                const bool interior = (kb < qt);

                float p[4][4];
#pragma unroll
                for (int nt = 0; nt < 4; nt++) {
                    bf16x8 kh0 = *(const bf16x8*)&Khs[cur][(nt * 16 + c16) * 32 + quad * 8];
                    bf16x8 kh1 = *(const bf16x8*)&Khs[cur][2048 + (nt * 16 + c16) * 32 + quad * 8];
                    bf16x8 kl0 = *(const bf16x8*)&Kls[cur][(nt * 16 + c16) * 32 + quad * 8];
                    bf16x8 kl1 = *(const bf16x8*)&Kls[cur][2048 + (nt * 16 + c16) * 32 + quad * 8];
                    f32x4 sa = (f32x4){0.f, 0.f, 0.f, 0.f};
                    sa = MFMA(qh0, kh0, sa);
                    sa = MFMA(qh1, kh1, sa);
                    sa = MFMA(ql0, kh0, sa);
                    sa = MFMA(ql1, kh1, sa);
                    sa = MFMA(qh0, kl0, sa);
                    sa = MFMA(qh1, kl1, sa);
                    const int key = k0 + nt * 16 + c16;
                    const bool mok = (mk[nt] != 0);
#pragma unroll
                    for (int reg = 0; reg < 4; reg++) {
                        int qg = q0 + wave * 16 + quad * 4 + reg;
                        float x = sa[reg];                       // pre-scaled by 1/8 via Q
                        float e1 = __expf(2.f * x);              // inf-safe (p->1)
                        float r  = __builtin_amdgcn_rcpf(e1 + 1.f);
                        float pv = __expf(-60.f * r);            // e^{30 tanh(x)-30}
                        bool keep = mok && (interior || key <= qg);
                        pv = keep ? pv : 0.f;
                        p[nt][reg] = pv;
                        rsl[reg] += pv;
                    }
                }

                // P: C-layout -> A-layout via wave-private LDS rows (in-order DS pipe)
#pragma unroll
                for (int nt = 0; nt < 4; nt++) {
                    int kl_ = nt * 16 + c16, sub = kl_ >> 5, kc = kl_ & 31;
#pragma unroll
                    for (int reg = 0; reg < 4; reg++)
                        Ps[sub * 2048 + (wave * 16 + quad * 4 + reg) * 32 + kc] = bf16rne(p[nt][reg]);
                }
                bf16x8 p0 = *(const bf16x8*)&Ps[(wave * 16 + c16) * 32 + quad * 8];
                bf16x8 p1 = *(const bf16x8*)&Ps[2048 + (wave * 16 + c16) * 32 + quad * 8];
#pragma unroll
                for (int dt = 0; dt < 4; dt++) {
                    o[dt] = MFMA(p0, vf[dt][0], o[dt]);
                    o[dt] = MFMA(p1, vf[dt][1], o[dt]);
                }
                cur ^= 1;
            }
        }
        __syncthreads();   // all K reads done before next tile's staging reuses buf 0

        // partial epilogue: o (bf16) and l (f32) per (sp, bh, qt)
        const size_t obase = (((size_t)sp * 1024 + (size_t)bh * 32 + qt) * 4096);
        const size_t lbase = (((size_t)sp * 1024 + (size_t)bh * 32 + qt) * 64);
        float lsum[4];
#pragma unroll
        for (int reg = 0; reg < 4; reg++) {
            float v = rsl[reg];
#pragma unroll
            for (int off = 1; off < 16; off <<= 1)
                v += __shfl_xor(v, off);
            lsum[reg] = v;
        }
        if (c16 == 0) {
#pragma unroll
            for (int reg = 0; reg < 4; reg++)
                Lp[lbase + wave * 16 + quad * 4 + reg] = lsum[reg];
        }
#pragma unroll
        for (int dt = 0; dt < 4; dt++)
#pragma unroll
            for (int reg = 0; reg < 4; reg++) {
                int row = wave * 16 + quad * 4 + reg;
                int d = dt * 16 + c16;
                Op[obase + row * 64 + d] = bf16rne(o[dt][reg]);
            }
    }
}

// ---------------- Kernel 3: combine ksplit partials ----------------
__global__ __launch_bounds__(256) void combine(
    const u16* __restrict__ Op, const float* __restrict__ Lp,
    float* __restrict__ Out)
{
    const int i = blockIdx.x * 256 + threadIdx.x;   // 1048576 threads, 4 floats each
    const size_t lin = (size_t)i * 4;
    const int d  = (int)(lin & 1023);
    const int h  = d >> 6, dd = d & 63;
    const int l  = (int)((lin >> 10) & 2047);
    const int b  = (int)(lin >> 21);
    const int qt = l >> 6, row = l & 63;
    const int bh = b * 16 + h;
    const size_t o0 = (((size_t)bh * 32 + qt) * 4096) + row * 64 + dd;
    const size_t o1 = o0 + (size_t)1024 * 4096;
    const size_t l0 = (((size_t)bh * 32 + qt) * 64) + row;
    ushort4 pa = *(const ushort4*)&Op[o0];
    ushort4 pb = *(const ushort4*)&Op[o1];
    float inv = __builtin_amdgcn_rcpf(Lp[l0] + Lp[l0 + 65536]);
    float4 r;
    r.x = (bf16f(pa.x) + bf16f(pb.x)) * inv;
    r.y = (bf16f(pa.y) + bf16f(pb.y)) * inv;
    r.z = (bf16f(pa.z) + bf16f(pb.z)) * inv;
    r.w = (bf16f(pa.w) + bf16f(pb.w)) * inv;
    *(float4*)&Out[lin] = r;
}

extern "C" void kernel_launch(void* const* d_in, const int* in_sizes, int n_in,
                              void* d_out, int out_size, void* d_ws, size_t ws_size,
                              hipStream_t stream) {
    const float* X  = (const float*)d_in[0];
    const int*   AM = (const int*)d_in[1];
    const float* Wq = (const float*)d_in[2];
    const float* Wk = (const float*)d_in[3];
    const float* Wv = (const float*)d_in[4];
    float* out = (float*)d_out;

    const size_t NE = (size_t)2 * 16 * 2048 * 64;   // 4.19M elems
    const size_t WN = (size_t)1024 * 1024;
    u16* Qh  = (u16*)d_ws;
    u16* Ql  = Qh + NE;
    u16* Kh  = Ql + NE;
    u16* Kl  = Kh + NE;
    u16* VT  = Kl + NE;
    u16* Xh  = VT + NE;      // dead after qkv_gemm -> reused as Op (2*NE u16)
    u16* Xl  = Xh + NE;
    u16* Wqh = Xl + NE;      // dead after qkv_gemm -> reused as Lp (131072 f32)
    u16* Wql = Wqh + WN;
    u16* Wkh = Wql + WN;
    u16* Wkl = Wkh + WN;
    u16* Wvh = Wkl + WN;     // ~69.2 MB total
    u16*   Op = Xh;
    float* Lp = (float*)Wqh;

    presplit<<<7168, 256, 0, stream>>>(X, Wq, Wk, Wv, Xh, Xl, Wqh, Wql, Wkh, Wkl, Wvh);
    qkv_gemm<<<768, 256, 0, stream>>>(Xh, Xl, Wqh, Wql, Wkh, Wkl, Wvh,
                                      Qh, Ql, Kh, Kl, VT);
    attn<<<dim3(32, 16, 2), 256, 0, stream>>>(Qh, Ql, Kh, Kl, VT, AM, Op, Lp);
    combine<<<4096, 256, 0, stream>>>(Op, Lp, out);
}